// Round 14
// baseline (5376.353 us; speedup 1.0000x reference)
//
#include <hip/hip_runtime.h>
#include <hip/hip_bf16.h>

#define B_SZ 1024
#define T_SZ 128
#define D_SZ 256
#define H_SZ 512
#define NBLK 256
#define NTHR 512
#define AUXS 0x11  // SC0|SC1 state loads: bypass reader L1/L2 (stale hazard
                   // cross-XCD), served by L3 (state set ~6.5MB << 256MB)

typedef __attribute__((ext_vector_type(8))) short short8;
typedef __attribute__((ext_vector_type(4))) float f32x4;

__device__ inline f32x4 mfma16(short8 a, short8 b, f32x4 c) {
  return __builtin_amdgcn_mfma_f32_16x16x32_bf16(a, b, c, 0, 0, 0);
}

// state store: write-through to L3 (r8-proven visibility for cross-XCD
// consumers), retired by vmcnt(0) before the strip barrier signals.
__device__ inline void st_bf16(__hip_bfloat16* p, float v) {
  union { __hip_bfloat16 b; unsigned short u; } cv;
  cv.b = __float2bfloat16(v);
  unsigned int vv = cv.u;
  asm volatile("global_store_short %0, %1, off sc0 sc1" :: "v"(p), "v"(vv) : "memory");
}

// Stage ROWSx64 bf16 tile -> LDS [ROWS][64], slot-swizzled (slot s of row r
// holds k-slot s^(r&7)); linear LDS dest + inverse-swizzled global source.
// 512-thread block: ROWS=32 -> waves 0-3 issue 1 instr; ROWS=64 -> all waves.
template <int ROWS, int AUX>
__device__ __forceinline__ void stage512(const __hip_bfloat16* __restrict__ src,
                                         int strideElts, int row0, int k0,
                                         unsigned short* lds, int tid) {
  constexpr int CH = ROWS * 8;
#pragma unroll
  for (int it = 0; it * NTHR < CH; ++it) {
    int wbase = it * NTHR + ((tid >> 6) << 6);
    if (wbase < CH) {
      int chunk = it * NTHR + tid;
      int row = chunk >> 3, slot = chunk & 7;
      int ksrc = (slot ^ (row & 7)) << 3;
      const __hip_bfloat16* g = src + (size_t)(row0 + row) * strideElts + (k0 + ksrc);
      unsigned short* l = lds + (size_t)wbase * 8;
      __builtin_amdgcn_global_load_lds(
          (const __attribute__((address_space(1))) unsigned int*)g,
          (__attribute__((address_space(3))) unsigned int*)l, 16, 0, AUX);
    }
  }
}

__device__ __forceinline__ short8 ldfrag(const unsigned short* lds, int row, int slot) {
  int s = slot ^ (row & 7);
  return *(const short8*)(lds + row * 64 + s * 8);
}

// Counted-vmcnt mainloop, 8 waves. A depth-4 (5 buffers, waves 0-3 issue, 1
// instr each), B depth-3 (4 buffers, B0..2 prestaged pre-gloop, PB instrs per
// wave per tile). Per-iter order: wait, barrier, sb(kt+3), sa(kt+4), cc(kt).
// In-order vmcnt per wave class:
//  waves 0-3: kt=0 vmcnt(3); kt=1 vmcnt(3+PB); 2..NT-4 vmcnt(3+2PB);
//             NT-3 vmcnt(2+2PB); NT-2 vmcnt(1+PB); NT-1 vmcnt(0)
//  waves 4-7 (B only): <=NT-3 vmcnt(2PB); NT-2 vmcnt(PB); NT-1 vmcnt(0)
template <int NT, int PB, typename SA, typename SB, typename CC>
__device__ __forceinline__ void gloop(int wv, SA sa, SB sb, CC cc) {
  sa(0, 0); sa(1, 1); sa(2, 2); sa(3, 3);   // waves 4-7 no-op internally
#pragma unroll 1
  for (int kt = 0; kt < NT; ++kt) {
    if (wv < 4) {
      if (kt == 0)           asm volatile("s_waitcnt vmcnt(3)" ::: "memory");
      else if (kt == 1)      asm volatile("s_waitcnt vmcnt(%0)" :: "i"(3 + PB) : "memory");
      else if (kt <= NT - 4) asm volatile("s_waitcnt vmcnt(%0)" :: "i"(3 + 2 * PB) : "memory");
      else if (kt == NT - 3) asm volatile("s_waitcnt vmcnt(%0)" :: "i"(2 + 2 * PB) : "memory");
      else if (kt == NT - 2) asm volatile("s_waitcnt vmcnt(%0)" :: "i"(1 + PB) : "memory");
      else                   asm volatile("s_waitcnt vmcnt(0)" ::: "memory");
    } else {
      if (kt <= NT - 3)      asm volatile("s_waitcnt vmcnt(%0)" :: "i"(2 * PB) : "memory");
      else if (kt == NT - 2) asm volatile("s_waitcnt vmcnt(%0)" :: "i"(PB) : "memory");
      else                   asm volatile("s_waitcnt vmcnt(0)" ::: "memory");
    }
    __builtin_amdgcn_s_barrier();
    __builtin_amdgcn_sched_barrier(0);
    if (kt + 3 < NT) sb(kt + 3, (kt + 3) & 3);
    if (kt + 4 < NT) sa(kt + 4, (kt + 4) % 5);
    cc(kt % 5, kt & 3);
  }
}

// Strip barrier split: arrive (drain stores) -> [prestage weights during the
// poll] -> wait. Monotonic counter, relaxed atomics (r5-r13 proven).
__device__ __forceinline__ void sbar_arrive(unsigned* scnt) {
  asm volatile("s_waitcnt vmcnt(0)" ::: "memory");  // all waves drain stores
  __syncthreads();
  if (threadIdx.x == 0)
    __hip_atomic_fetch_add(scnt, 1u, __ATOMIC_RELAXED, __HIP_MEMORY_SCOPE_AGENT);
}
__device__ __forceinline__ void sbar_wait(unsigned* scnt, unsigned p) {
  if (threadIdx.x == 0) {
    while (__hip_atomic_load(scnt, __ATOMIC_RELAXED, __HIP_MEMORY_SCOPE_AGENT) < p * 8u)
      __builtin_amdgcn_s_sleep(1);
  }
  __syncthreads();
  __builtin_amdgcn_sched_barrier(0);
}

__global__ __launch_bounds__(512, 2) void k_fused(
    const float* __restrict__ xg, const float* __restrict__ xtime,
    const __hip_bfloat16* __restrict__ W1t, const float* __restrict__ b1,
    const __hip_bfloat16* __restrict__ W2t, const float* __restrict__ b2,
    const __hip_bfloat16* __restrict__ Wzrt, const float* __restrict__ bz,
    const float* __restrict__ br, const __hip_bfloat16* __restrict__ Wnt,
    const float* __restrict__ bn, float* __restrict__ hf, float* __restrict__ hstdf,
    __hip_bfloat16* __restrict__ hbf, __hip_bfloat16* __restrict__ Ubf,
    __hip_bfloat16* __restrict__ hodeb, __hip_bfloat16* __restrict__ hstdb,
    __hip_bfloat16* __restrict__ A4, __hip_bfloat16* __restrict__ xstep,
    unsigned* __restrict__ bar) {
  __shared__ __align__(16) unsigned short lA[5][32 * 64];    // 20 KB, A depth-4
  __shared__ __align__(16) unsigned short lB[4][128 * 64];   // 64 KB, B depth-3
  int tid = threadIdx.x, lane = tid & 63, wv = tid >> 6;
  int lr = lane & 15, lg = lane >> 4;
  int rh = wv >> 2, cq = wv & 3;   // wave role: row-half (0/1), col-quarter
  int b = blockIdx.x;
  // SLICE-per-XCD mapping: column-slice s = b&7 rides the XCD round-robin, so
  // each XCD touches only its 768 KB weight slice -> L2-resident across all
  // 128 steps (no thrash). Strips spread across XCDs; state exchange goes
  // through L3 via sc0sc1 (correct regardless of placement — heuristic only
  // affects speed).
  int s = b & 7;                   // slice 0..7 (pinned per XCD)
  int i = b >> 3;                  // strip 0..31
  int m0 = i << 5;                 // 32-row strip
  int nA = s << 6;                 // owned 64-column base (ALL phases)
  unsigned* scnt = bar + i * 32;
  unsigned p = 0;
  // per-thread owned cell: rows m0+(rh*16)+(lg*4+r), col nA+(cq*16)+lr.
  // ALL f32 state (h, hstd, h_ode, z) lives in these registers.
  int cl = (cq << 4) + lr;
  int col = nA + cl;
  int row0 = m0 + (rh << 4) + (lg << 2);
  float hreg[4] = {0.f, 0.f, 0.f, 0.f}, sreg[4] = {0.f, 0.f, 0.f, 0.f};
  float oreg[4], zreg[4];

  // prestage P1 weight tiles 0..2
  stage512<64, 0>(W1t, H_SZ, nA, 0, lB[0], tid);
  stage512<64, 0>(W1t, H_SZ, nA, 64, lB[1], tid);
  stage512<64, 0>(W1t, H_SZ, nA, 128, lB[2], tid);

#pragma unroll 1
  for (int t = 0; t < T_SZ; ++t) {
    // ======== P1: U = tanh(h @ W1 + b1), owned cols ========
    {
      f32x4 acc = {};
      auto sa = [&](int kt, int bi) { stage512<32, AUXS>(hbf, H_SZ, m0, kt << 6, lA[bi], tid); };
      auto sb = [&](int kt, int bi) { stage512<64, 0>(W1t, H_SZ, nA, kt << 6, lB[bi], tid); };
      auto cc = [&](int ai, int bi) {
#pragma unroll
        for (int kk = 0; kk < 2; ++kk) {
          short8 a = ldfrag(lA[ai], (rh << 4) + lr, (kk << 2) + lg);
          short8 bb = ldfrag(lB[bi], cl, (kk << 2) + lg);
          acc = mfma16(a, bb, acc);
        }
      };
      gloop<8, 1>(wv, sa, sb, cc);
      float bi = b1[col];
#pragma unroll
      for (int r = 0; r < 4; ++r)
        st_bf16(&Ubf[(size_t)(row0 + r) * H_SZ + col], tanhf(acc[r] + bi));
    }
    sbar_arrive(scnt);
    stage512<64, 0>(W2t, H_SZ, nA, 0, lB[0], tid);
    stage512<64, 0>(W2t, H_SZ, nA, 64, lB[1], tid);
    stage512<64, 0>(W2t, H_SZ, nA, 128, lB[2], tid);
    sbar_wait(scnt, ++p);
    // ======== P2: h_ode = h + dt*(U @ W2 + b2); x slice -> bf16 ========
    {
      f32x4 acc = {};
      auto sa = [&](int kt, int bi) { stage512<32, AUXS>(Ubf, H_SZ, m0, kt << 6, lA[bi], tid); };
      auto sb = [&](int kt, int bi) { stage512<64, 0>(W2t, H_SZ, nA, kt << 6, lB[bi], tid); };
      auto cc = [&](int ai, int bi) {
#pragma unroll
        for (int kk = 0; kk < 2; ++kk) {
          short8 a = ldfrag(lA[ai], (rh << 4) + lr, (kk << 2) + lg);
          short8 bb = ldfrag(lB[bi], cl, (kk << 2) + lg);
          acc = mfma16(a, bb, acc);
        }
      };
      gloop<8, 1>(wv, sa, sb, cc);
      float dtv = (t == 0) ? 0.01f : (xtime[t] - xtime[t - 1]);
      float bi = b2[col];
#pragma unroll
      for (int r = 0; r < 4; ++r) {
        float v = hreg[r] + dtv * (acc[r] + bi);
        oreg[r] = v;
        st_bf16(&hodeb[(size_t)(row0 + r) * H_SZ + col], v);
      }
      {  // x[:, t, s-slice] -> bf16 (32 strip rows, 32 cols per slice)
        int colx = (s << 5) + (tid & 31);
#pragma unroll
        for (int it2 = 0; it2 < 2; ++it2) {
          int row = m0 + (tid >> 5) + (it2 << 4);
          float xv = xg[((size_t)row * T_SZ + t) * D_SZ + colx];
          st_bf16(&xstep[(size_t)row * D_SZ + colx], xv);
        }
      }
    }
    sbar_arrive(scnt);
#pragma unroll
    for (int q = 0; q < 3; ++q) {  // prestage P3 B0..2 ([z-half | r-half])
      stage512<64, 0>(Wzrt, 1280, nA, q << 6, lB[q], tid);
      stage512<64, 0>(Wzrt, 1280, 512 + nA, q << 6, lB[q] + 64 * 64, tid);
    }
    sbar_wait(scnt, ++p);
    // ======== P3: z,r = sigmoid(cat @ WzrT), owned cols; build A4 ========
    {
      f32x4 acc0 = {}, acc1 = {};
      auto sa = [&](int kt, int bi) {
        int ke = kt << 6;
        if (ke < 512)       stage512<32, AUXS>(hodeb, H_SZ, m0, ke, lA[bi], tid);
        else if (ke < 1024) stage512<32, AUXS>(hstdb, H_SZ, m0, ke - 512, lA[bi], tid);
        else                stage512<32, AUXS>(xstep, D_SZ, m0, ke - 1024, lA[bi], tid);
      };
      auto sb = [&](int kt, int bi) {
        stage512<64, 0>(Wzrt, 1280, nA, kt << 6, lB[bi], tid);
        stage512<64, 0>(Wzrt, 1280, 512 + nA, kt << 6, lB[bi] + 64 * 64, tid);
      };
      auto cc = [&](int ai, int bi) {
#pragma unroll
        for (int kk = 0; kk < 2; ++kk) {
          short8 a = ldfrag(lA[ai], (rh << 4) + lr, (kk << 2) + lg);
          short8 b0 = ldfrag(lB[bi], cl, (kk << 2) + lg);          // z-cols
          short8 b1f = ldfrag(lB[bi], 64 + cl, (kk << 2) + lg);    // r-cols
          acc0 = mfma16(a, b0, acc0);
          acc1 = mfma16(a, b1f, acc1);
        }
      };
      gloop<20, 2>(wv, sa, sb, cc);
      float bz_ = bz[col], br_ = br[col];
#pragma unroll
      for (int r = 0; r < 4; ++r) {
        int row = row0 + r;
        zreg[r] = 1.f / (1.f + expf(-(acc0[r] + bz_)));
        float g = 1.f / (1.f + expf(-(acc1[r] + br_)));
        st_bf16(&A4[(size_t)row * 1024 + col], oreg[r] * g);
        st_bf16(&A4[(size_t)row * 1024 + 512 + col], sreg[r] * g);
      }
    }
    sbar_arrive(scnt);
#pragma unroll
    for (int q = 0; q < 3; ++q) {  // prestage P4 B0..2 ([mean | std])
      stage512<64, 0>(Wnt, 1280, nA, q << 6, lB[q], tid);
      stage512<64, 0>(Wnt, 1280, 512 + nA, q << 6, lB[q] + 64 * 64, tid);
    }
    sbar_wait(scnt, ++p);
    // ======== P4: n_mean,n_std owned cols; GRU update in registers ========
    {
      f32x4 acc0 = {}, acc1 = {};
      auto sa = [&](int kt, int bi) {
        int ke = kt << 6;
        if (ke < 1024) stage512<32, AUXS>(A4, 1024, m0, ke, lA[bi], tid);
        else           stage512<32, AUXS>(xstep, D_SZ, m0, ke - 1024, lA[bi], tid);
      };
      auto sb = [&](int kt, int bi) {
        stage512<64, 0>(Wnt, 1280, nA, kt << 6, lB[bi], tid);
        stage512<64, 0>(Wnt, 1280, 512 + nA, kt << 6, lB[bi] + 64 * 64, tid);
      };
      auto cc = [&](int ai, int bi) {
#pragma unroll
        for (int kk = 0; kk < 2; ++kk) {
          short8 a = ldfrag(lA[ai], (rh << 4) + lr, (kk << 2) + lg);
          short8 b0 = ldfrag(lB[bi], cl, (kk << 2) + lg);          // mean
          short8 b1f = ldfrag(lB[bi], 64 + cl, (kk << 2) + lg);    // std
          acc0 = mfma16(a, b0, acc0);
          acc1 = mfma16(a, b1f, acc1);
        }
      };
      gloop<20, 2>(wv, sa, sb, cc);
      float bm = bn[col], bs = bn[512 + col];
#pragma unroll
      for (int r = 0; r < 4; ++r) {
        int row = row0 + r;
        float z = zreg[r];
        float hn = (1.f - z) * (acc0[r] + bm) + z * oreg[r];
        hreg[r] = hn;
        st_bf16(&hbf[(size_t)row * H_SZ + col], hn);
        float ns = fabsf(acc1[r] + bs);
        float sn = fabsf((1.f - z) * ns + z * sreg[r]);
        sreg[r] = sn;
        st_bf16(&hstdb[(size_t)row * H_SZ + col], sn);
      }
    }
    sbar_arrive(scnt);
    stage512<64, 0>(W1t, H_SZ, nA, 0, lB[0], tid);   // prestage next P1 B0..2
    stage512<64, 0>(W1t, H_SZ, nA, 64, lB[1], tid);
    stage512<64, 0>(W1t, H_SZ, nA, 128, lB[2], tid);
    sbar_wait(scnt, ++p);
  }
  // final output: register state -> global
#pragma unroll
  for (int r = 0; r < 4; ++r) {
    int row = row0 + r;
    hf[(size_t)row * H_SZ + col] = hreg[r];
    hstdf[(size_t)row * H_SZ + col] = sreg[r];
  }
}

// =============== prep: W[k][n] f32  ->  Wt[n][k] bf16 =====================
__global__ void k_wt(const float* __restrict__ W, __hip_bfloat16* __restrict__ Wt,
                     int K, int N, int ld) {
  size_t i = (size_t)blockIdx.x * 256 + threadIdx.x;
  if (i >= (size_t)K * N) return;
  int n = (int)(i / K), k = (int)(i % K);
  Wt[(size_t)n * ld + k] = __float2bfloat16(W[(size_t)k * N + n]);
}

extern "C" void kernel_launch(void* const* d_in, const int* in_sizes, int n_in,
                              void* d_out, int out_size, void* d_ws, size_t ws_size,
                              hipStream_t stream) {
  const float* x     = (const float*)d_in[0];
  const float* xtime = (const float*)d_in[1];
  const float* W1    = (const float*)d_in[2];
  const float* b1    = (const float*)d_in[3];
  const float* W2    = (const float*)d_in[4];
  const float* b2    = (const float*)d_in[5];
  const float* Wz    = (const float*)d_in[6];
  const float* bz    = (const float*)d_in[7];
  const float* Wr    = (const float*)d_in[8];
  const float* br    = (const float*)d_in[9];
  const float* Wn    = (const float*)d_in[10];
  const float* bn    = (const float*)d_in[11];

  char* p = (char*)d_ws;
  __hip_bfloat16* W1t   = (__hip_bfloat16*)(p + 0);
  __hip_bfloat16* W2t   = (__hip_bfloat16*)(p + 524288);
  __hip_bfloat16* Wzrt  = (__hip_bfloat16*)(p + 1048576);
  __hip_bfloat16* Wnt   = (__hip_bfloat16*)(p + 3670016);
  float*          hf    = (float*)(p + 6291456);
  float*          hstdf = (float*)(p + 8388608);
  __hip_bfloat16* hbf   = (__hip_bfloat16*)(p + 14680064);
  __hip_bfloat16* Ubf   = (__hip_bfloat16*)(p + 15728640);
  __hip_bfloat16* hodeb = (__hip_bfloat16*)(p + 16777216);
  __hip_bfloat16* hstdb = (__hip_bfloat16*)(p + 17825792);
  __hip_bfloat16* A4    = (__hip_bfloat16*)(p + 18874368);
  __hip_bfloat16* xstep = (__hip_bfloat16*)(p + 20971520);
  unsigned*       bar   = (unsigned*)(p + 21495808);

  hipMemsetAsync(hbf, 0, 1048576, stream);
  hipMemsetAsync(hstdb, 0, 1048576, stream);
  hipMemsetAsync(bar, 0, 8192, stream);

  k_wt<<<(512 * 512 + 255) / 256, 256, 0, stream>>>(W1, W1t, 512, 512, 512);
  k_wt<<<(512 * 512 + 255) / 256, 256, 0, stream>>>(W2, W2t, 512, 512, 512);
  k_wt<<<(1280 * 512 + 255) / 256, 256, 0, stream>>>(Wz, Wzrt, 1280, 512, 1280);
  k_wt<<<(1280 * 512 + 255) / 256, 256, 0, stream>>>(Wr, Wzrt + (size_t)512 * 1280, 1280, 512, 1280);
  k_wt<<<(1280 * 1024 + 255) / 256, 256, 0, stream>>>(Wn, Wnt, 1280, 1024, 1280);

  // persistent kernel: slice-per-XCD weights (L2-resident, no thrash), strips
  // spread; register f32 state; cross-XCD bf16 state via L3 (sc0sc1 both ways)
  k_fused<<<NBLK, NTHR, 0, stream>>>(x, xtime, W1t, b1, W2t, b2, Wzrt, bz, br,
                                     Wnt, bn, hf, hstdf, hbf, Ubf,
                                     hodeb, hstdb, A4, xstep, bar);

  hipMemcpyAsync(d_out, hf, 2097152, hipMemcpyDeviceToDevice, stream);
  hipMemcpyAsync((char*)d_out + 2097152, hstdf, 2097152, hipMemcpyDeviceToDevice, stream);
}